// Round 7
// baseline (22.950 us; speedup 1.0000x reference)
//
#include <hip/hip_runtime.h>
#include <hip/hip_bf16.h>

#define S_LEN 512
#define H_DIM 768
#define BS_TOK 8192      // B*S
#define NCOLS 80
#define KSPLIT 4
#define KSEG 192         // K per segment
#define PSTRIDE 72       // fp16 partial row stride (144B)
#define TOKB 32          // tokens per block in epilogue kernel
// fragment image: [seg][ks<6][nt<5][lane<64][e<8] bf16 = 61440 elems
#define FRAG_ELEMS (KSPLIT * 6 * 5 * 64 * 8)

typedef __attribute__((ext_vector_type(8))) short short8v;
typedef __attribute__((ext_vector_type(4))) short short4v;
typedef __attribute__((ext_vector_type(4))) float f32x4;
typedef __attribute__((ext_vector_type(4))) _Float16 h4;

__device__ __forceinline__ short f2bf(float f) {
  union { float f; unsigned u; } x; x.f = f;
  unsigned r = x.u + 0x7fffu + ((x.u >> 16) & 1u);
  return (short)(r >> 16);
}

__device__ __forceinline__ short bfc(float f) {
  __hip_bfloat16 b = __float2bfloat16(f);   // RTNE; pairs fuse to v_cvt_pk_bf16_f32
  return *reinterpret_cast<short*>(&b);
}

// ===== kprepF: build B in MFMA-fragment order =====
// elem i = ((sk*5 + nt)*64 + lane)*8 + e,  sk = seg*6+ks
// k = sk*32 + (lane>>4)*8 + e ; c = nt*16 + (lane&15)
__global__ __launch_bounds__(256) void kprepF(const float* __restrict__ tw,
                                              const float* __restrict__ w1,
                                              const float* __restrict__ wsc,
                                              short* __restrict__ wf) {
  int i = blockIdx.x * 256 + threadIdx.x;
  if (i >= FRAG_ELEMS) return;
  int e    = i & 7;
  int lane = (i >> 3) & 63;
  int rest = i >> 9;
  int nt   = rest % 5;
  int sk   = rest / 5;
  int k    = sk * 32 + (lane >> 4) * 8 + e;
  int c    = nt * 16 + (lane & 15);
  float v = 0.f;
  if (c < 64)       v = tw[k] * w1[(size_t)k * 64 + c];
  else if (c < 66)  v = wsc[(size_t)k * 2 + (c - 64)];
  wf[i] = f2bf(v);
}

// ===== kG: barrier-free, LDS-free MFMA GEMM; one wave = 16 rows x 1 K-seg =====
__global__ __launch_bounds__(256) void kG(const float* __restrict__ hidden,
                                          const short* __restrict__ wf,
                                          _Float16* __restrict__ part) {
  const int tid  = threadIdx.x;
  const int wv   = blockIdx.x * 4 + (tid >> 6);  // 0..2047
  const int lane = tid & 63;
  const int seg  = wv & 3;
  const int tile = wv >> 2;                      // 0..511
  const int ci   = lane & 15;
  const int g    = lane >> 4;
  const int r0   = tile * 16;

  // issue all 12 A loads up front (independent, stay in flight)
  const float* aptr = hidden + (size_t)(r0 + ci) * H_DIM + seg * KSEG + g * 8;
  float4 abuf[12];
#pragma unroll
  for (int q = 0; q < 6; ++q) {
    abuf[2 * q]     = *reinterpret_cast<const float4*>(aptr + q * 32);
    abuf[2 * q + 1] = *reinterpret_cast<const float4*>(aptr + q * 32 + 4);
  }

  const short8v* bf = reinterpret_cast<const short8v*>(wf) + (size_t)seg * 6 * 5 * 64 + lane;

  f32x4 acc[5];
#pragma unroll
  for (int nt = 0; nt < 5; ++nt) acc[nt] = (f32x4){0.f, 0.f, 0.f, 0.f};

#pragma unroll
  for (int ks = 0; ks < 6; ++ks) {
    const float4 a0 = abuf[2 * ks];
    const float4 a1 = abuf[2 * ks + 1];
    short8v av;
    av[0] = bfc(a0.x); av[1] = bfc(a0.y); av[2] = bfc(a0.z); av[3] = bfc(a0.w);
    av[4] = bfc(a1.x); av[5] = bfc(a1.y); av[6] = bfc(a1.z); av[7] = bfc(a1.w);
#pragma unroll
    for (int nt = 0; nt < 5; ++nt) {
      short8v bb = bf[(ks * 5 + nt) * 64];
      acc[nt] = __builtin_amdgcn_mfma_f32_16x16x32_bf16(av, bb, acc[nt], 0, 0, 0);
    }
  }

  _Float16* pr = part + ((size_t)seg * BS_TOK + r0) * PSTRIDE;
#pragma unroll
  for (int j = 0; j < 4; ++j) {
    int r = 4 * g + j;
#pragma unroll
    for (int nt = 0; nt < 4; ++nt)
      pr[r * PSTRIDE + nt * 16 + ci] = (_Float16)acc[nt][j];
    if (ci < 2) pr[r * PSTRIDE + 64 + ci] = (_Float16)acc[4][j];
  }
}

// ===== kB: fused partial-reduce + relu-MLP epilogue + prefix softmax =====
__global__ __launch_bounds__(256) void kB(const _Float16* __restrict__ part,
                                          const float* __restrict__ b1,
                                          const float* __restrict__ w2,
                                          const float* __restrict__ b2,
                                          const float* __restrict__ bsc,
                                          float* __restrict__ out) {
  __shared__ float lp[TOKB + 8][4];   // [logit, p0, p1, pad]
  const int tid  = threadIdx.x;
  const int t0   = blockIdx.x * TOKB;
  const int w    = tid >> 6;
  const int lane = tid & 63;
  const int ci   = lane & 15;
  const int grp  = lane >> 4;
  const int base = w * 4 + grp;       // 0..15 token-slot per pass

#pragma unroll
  for (int pass = 0; pass < 3; ++pass) {
    int slot = pass * 16 + base;
    if (slot < TOKB + 7) {
      int tt = min(t0 + slot, BS_TOK - 1);
      h4 v[KSPLIT];
#pragma unroll
      for (int seg = 0; seg < KSPLIT; ++seg)
        v[seg] = *reinterpret_cast<const h4*>(
            part + ((size_t)seg * BS_TOK + tt) * PSTRIDE + 4 * ci);
      f32x4 s = (f32x4){0.f, 0.f, 0.f, 0.f};
#pragma unroll
      for (int seg = 0; seg < KSPLIT; ++seg) {
        s[0] += (float)v[seg][0]; s[1] += (float)v[seg][1];
        s[2] += (float)v[seg][2]; s[3] += (float)v[seg][3];
      }
      float pv = 0.f;
      if (ci < 2) {
#pragma unroll
        for (int seg = 0; seg < KSPLIT; ++seg)
          pv += (float)part[((size_t)seg * BS_TOK + tt) * PSTRIDE + 64 + ci];
      }
      const float4 bb = *reinterpret_cast<const float4*>(b1 + 4 * ci);
      const float4 ww = *reinterpret_cast<const float4*>(w2 + 4 * ci);
      float r = fmaxf(s[0] + bb.x, 0.f) * ww.x + fmaxf(s[1] + bb.y, 0.f) * ww.y +
                fmaxf(s[2] + bb.z, 0.f) * ww.z + fmaxf(s[3] + bb.w, 0.f) * ww.w;
#pragma unroll
      for (int msk = 1; msk < 16; msk <<= 1) r += __shfl_xor(r, msk, 64);
      if (ci == 0) lp[slot][0] = r + b2[0];
      if (ci < 2)  lp[slot][1 + ci] = pv;
    }
  }
  __syncthreads();

  if (tid < TOKB) {
    int t = t0 + tid;
    int s_ = t & (S_LEN - 1);
    int nmax = min(8, S_LEN - s_);
    float bs0 = bsc[0], bs1 = bsc[1];
    float m = lp[tid][0];
    float d = 1.f;
    float n0 = lp[tid][1], n1 = lp[tid][2];
    float o[16];
    o[0] = n0 + bs0; o[1] = n1 + bs1;
#pragma unroll
    for (int j = 1; j < 8; ++j) {
      if (j < nmax) {
        float L  = lp[tid + j][0];
        float nm = fmaxf(m, L);
        float sc = __expf(m - nm);
        float e  = __expf(L - nm);
        d  = d  * sc + e;
        n0 = n0 * sc + e * lp[tid + j][1];
        n1 = n1 * sc + e * lp[tid + j][2];
        m = nm;
      }
      float inv = 1.f / d;
      o[2 * j]     = n0 * inv + bs0;
      o[2 * j + 1] = n1 * inv + bs1;
    }
    float4* op = reinterpret_cast<float4*>(out + (size_t)t * 16);
#pragma unroll
    for (int i = 0; i < 4; ++i) op[i] = *reinterpret_cast<float4*>(&o[4 * i]);
  }
}

// ===== fallback path (tiny ws) =====

__global__ __launch_bounds__(256) void kprepS(const float* __restrict__ tw,
                                              const float* __restrict__ w1,
                                              const float* __restrict__ wsc,
                                              short* __restrict__ wcat) {
  int i = blockIdx.x * 256 + threadIdx.x;
  if (i >= NCOLS * H_DIM) return;
  int c = i / H_DIM, k = i - c * H_DIM;
  float v = 0.f;
  if (c < 64)       v = tw[k] * w1[k * 64 + c];
  else if (c == 64) v = wsc[k * 2 + 0];
  else if (c == 65) v = wsc[k * 2 + 1];
  wcat[i] = f2bf(v);
}

__global__ __launch_bounds__(256) void k1s(const float* __restrict__ hidden,
                                           const short* __restrict__ wcat,
                                           const float* __restrict__ b1,
                                           const float* __restrict__ w2,
                                           const float* __restrict__ b2,
                                           float* __restrict__ logit,
                                           float* __restrict__ pbuf) {
  __shared__ short as[64 * 72];
  __shared__ short bss[NCOLS * 72];
  const int tid  = threadIdx.x;
  const int t0   = blockIdx.x * 64;
  const int w    = tid >> 6;
  const int lane = tid & 63;
  const int ci   = lane & 15;
  const int kg   = (lane >> 4) * 8;
  const int arow = w * 16 + ci;

  f32x4 acc[5];
#pragma unroll
  for (int nt = 0; nt < 5; ++nt) acc[nt] = (f32x4){0.f, 0.f, 0.f, 0.f};

  for (int cc = 0; cc < H_DIM / 64; ++cc) {
    const int k0 = cc * 64;
    __syncthreads();
#pragma unroll
    for (int i = 0; i < 4; ++i) {
      int f = tid + 256 * i;
      int r = f >> 4, c4 = f & 15;
      const float4 v = *reinterpret_cast<const float4*>(
          hidden + (size_t)(t0 + r) * H_DIM + k0 + c4 * 4);
      short4v bv;
      bv[0] = f2bf(v.x); bv[1] = f2bf(v.y); bv[2] = f2bf(v.z); bv[3] = f2bf(v.w);
      *reinterpret_cast<short4v*>(&as[r * 72 + c4 * 4]) = bv;
    }
    for (int i = tid; i < NCOLS * 8; i += 256) {
      int r = i >> 3, c8 = i & 7;
      short8v v = *reinterpret_cast<const short8v*>(wcat + r * H_DIM + k0 + c8 * 8);
      *reinterpret_cast<short8v*>(&bss[r * 72 + c8 * 8]) = v;
    }
    __syncthreads();
#pragma unroll
    for (int ks = 0; ks < 64; ks += 32) {
      short8v a = *reinterpret_cast<const short8v*>(&as[arow * 72 + ks + kg]);
#pragma unroll
      for (int nt = 0; nt < 5; ++nt) {
        short8v bb = *reinterpret_cast<const short8v*>(&bss[(nt * 16 + ci) * 72 + ks + kg]);
        acc[nt] = __builtin_amdgcn_mfma_f32_16x16x32_bf16(a, bb, acc[nt], 0, 0, 0);
      }
    }
  }

  const int g = lane >> 4;
  float lg[4];
#pragma unroll
  for (int j = 0; j < 4; ++j) {
    float sacc = 0.f;
#pragma unroll
    for (int nt = 0; nt < 4; ++nt) {
      int c = nt * 16 + ci;
      float z = acc[nt][j] + b1[c];
      z = fmaxf(z, 0.f);
      sacc += z * w2[c];
    }
#pragma unroll
    for (int msk = 1; msk < 16; msk <<= 1) sacc += __shfl_xor(sacc, msk, 64);
    lg[j] = sacc;
  }
  const float b2v = b2[0];
#pragma unroll
  for (int j = 0; j < 4; ++j) {
    int rg = t0 + w * 16 + 4 * g + j;
    if (ci == 0) {
      logit[rg] = lg[j] + b2v;
      pbuf[rg * 2 + 0] = acc[4][j];
    } else if (ci == 1) {
      pbuf[rg * 2 + 1] = acc[4][j];
    }
  }
}

__global__ __launch_bounds__(256) void k3g(const float* __restrict__ logit,
                                           const float* __restrict__ pbuf,
                                           const float* __restrict__ bsc,
                                           float* __restrict__ out) {
  int t = blockIdx.x * 256 + threadIdx.x;
  int s = t & (S_LEN - 1);
  int nmax = min(8, S_LEN - s);
  float bs0 = bsc[0], bs1 = bsc[1];
  float m = logit[t];
  float d = 1.f;
  float n0 = pbuf[2 * t], n1 = pbuf[2 * t + 1];
  float o[16];
  o[0] = n0 + bs0; o[1] = n1 + bs1;
#pragma unroll
  for (int j = 1; j < 8; ++j) {
    if (j < nmax) {
      float L  = logit[t + j];
      float nm = fmaxf(m, L);
      float sc = __expf(m - nm);
      float e  = __expf(L - nm);
      d  = d  * sc + e;
      n0 = n0 * sc + e * pbuf[2 * (t + j)];
      n1 = n1 * sc + e * pbuf[2 * (t + j) + 1];
      m = nm;
    }
    float inv = 1.f / d;
    o[2 * j]     = n0 * inv + bs0;
    o[2 * j + 1] = n1 * inv + bs1;
  }
  float4* op = reinterpret_cast<float4*>(out + (size_t)t * 16);
#pragma unroll
  for (int i = 0; i < 4; ++i) op[i] = *reinterpret_cast<float4*>(&o[4 * i]);
}

// ===== launch =====

extern "C" void kernel_launch(void* const* d_in, const int* in_sizes, int n_in,
                              void* d_out, int out_size, void* d_ws, size_t ws_size,
                              hipStream_t stream) {
  const float* hidden = (const float*)d_in[0];
  const float* tw     = (const float*)d_in[1];
  const float* w1     = (const float*)d_in[2];
  const float* b1     = (const float*)d_in[3];
  const float* w2     = (const float*)d_in[4];
  const float* b2     = (const float*)d_in[5];
  const float* wsc    = (const float*)d_in[6];
  const float* bsc    = (const float*)d_in[7];
  float* out = (float*)d_out;
  char* ws = (char*)d_ws;

  const size_t part_bytes = (size_t)KSPLIT * BS_TOK * PSTRIDE * 2;  // 4,718,592
  const size_t frag_bytes = (size_t)FRAG_ELEMS * 2;                 // 122,880
  const size_t need_fast  = part_bytes + frag_bytes;

  if (ws_size >= need_fast) {
    _Float16* part = (_Float16*)ws;
    short* wf      = (short*)(ws + part_bytes);
    kprepF<<<(FRAG_ELEMS + 255) / 256, 256, 0, stream>>>(tw, w1, wsc, wf);
    kG    <<<BS_TOK * KSPLIT / 16 / 4, 256, 0, stream>>>(hidden, wf, part);
    kB    <<<BS_TOK / TOKB, 256, 0, stream>>>(part, b1, w2, b2, bsc, out);
  } else {
    short* wcat  = (short*)ws;
    float* logit = (float*)(ws + 131072);
    float* pbuf  = (float*)(ws + 131072 + 32768);
    kprepS<<<(NCOLS * H_DIM + 255) / 256, 256, 0, stream>>>(tw, w1, wsc, wcat);
    k1s<<<BS_TOK / 64, 256, 0, stream>>>(hidden, wcat, b1, w2, b2, logit, pbuf);
    k3g<<<BS_TOK / 256, 256, 0, stream>>>(logit, pbuf, bsc, out);
  }
}